// Round 2
// baseline (222.268 us; speedup 1.0000x reference)
//
#include <hip/hip_runtime.h>
#include <hip/hip_bf16.h>

// h:[N,128] f32, src/dst:[E] i32, W1:[128,256] f32, b1:[128] f32, W2:[1,128] f32,
// b2,W3,b3: scalars f32  -> out:[E] f32
// Factorization: W1@concat(h[s],h[d]) = W1[:,:128]@h[s] + W1[:,128:]@h[d]
// Stage 1 (per node, MFMA bf16): AB[n][0:128] = W1[:,:128]@h[n] + b1 ; AB[n][128:256] = W1[:,128:]@h[n]
//   AB stored bf16 in d_ws (51.2 MB) to halve stage-2 gather traffic.
// Stage 2 (per edge): out = sigmoid(relu(W3*relu(W2 . relu(A[s]+B[d]) + b2) + b3))

#define HID 128

using short8 = __attribute__((ext_vector_type(8))) short;  // 8 bf16 = 4 VGPRs
using f32x4  = __attribute__((ext_vector_type(4))) float;

typedef unsigned int uint32;

static __device__ __forceinline__ unsigned short f2bf(float f) {  // RNE f32->bf16
    uint32 u = __float_as_uint(f);
    u += 0x7fffu + ((u >> 16) & 1u);
    return (unsigned short)(u >> 16);
}
static __device__ __forceinline__ float bflo(uint32 u) { return __uint_as_float(u << 16); }
static __device__ __forceinline__ float bfhi(uint32 u) { return __uint_as_float(u & 0xffff0000u); }

static __device__ __forceinline__ short8 cvt8(float4 a, float4 b) {
    short8 r;
    r[0] = (short)f2bf(a.x); r[1] = (short)f2bf(a.y);
    r[2] = (short)f2bf(a.z); r[3] = (short)f2bf(a.w);
    r[4] = (short)f2bf(b.x); r[5] = (short)f2bf(b.y);
    r[6] = (short)f2bf(b.z); r[7] = (short)f2bf(b.w);
    return r;
}

// ---------------------------------------------------------------------------
// Stage 1: node GEMM via MFMA.  D[o][n] = sum_k V[o][k] * h[n][k]
//   V[o][k] = W1[o&127][(o>=128?128:0)+k],  o in [0,256), k in [0,128)
// mfma_f32_16x16x32_bf16 (m89-verified): A[m=lane&15][k=quad*8+j],
//   B[k=quad*8+j][n=lane&15], C/D col=lane&15 (node), row=quad*4+reg (output)
//   -> 4 consecutive outputs/lane => contiguous 8B store.
// ---------------------------------------------------------------------------
#define NT_PER_BLOCK 10  // 16-node tiles per block

__global__ __launch_bounds__(256) void node_stage_kernel(
    const float* __restrict__ h,    // [N,128]
    const float* __restrict__ W1,   // [128,256]
    const float* __restrict__ b1,   // [128]
    unsigned short* __restrict__ AB, // [N,256] bf16 bits out
    int N)
{
    const int lane = threadIdx.x & 63;
    const int wave = threadIdx.x >> 6;   // 0..3 -> output group wave*64
    const int c    = lane & 15;
    const int q    = lane >> 4;

    // Loop-invariant weight A-frags (fp32 load -> bf16 frag, once per block)
    short8 vfrag[4][4];
    float  bias[4][4];
#pragma unroll
    for (int ot = 0; ot < 4; ++ot) {
#pragma unroll
        for (int ks = 0; ks < 4; ++ks) {
            int o   = wave * 64 + ot * 16 + c;
            int row = o & 127;
            int col = ((o >= 128) ? 128 : 0) + ks * 32 + q * 8;
            const float* p = W1 + row * 256 + col;
            vfrag[ot][ks] = cvt8(*(const float4*)p, *(const float4*)(p + 4));
        }
#pragma unroll
        for (int r = 0; r < 4; ++r) {
            int o = wave * 64 + ot * 16 + q * 4 + r;
            bias[ot][r] = (o < 128) ? b1[o] : 0.0f;
        }
    }

    const int nt0 = blockIdx.x * NT_PER_BLOCK;
    for (int it = 0; it < NT_PER_BLOCK; ++it) {
        int n0 = (nt0 + it) * 16;
        if (n0 + 16 > N) break;  // N=100000 is a multiple of 16

        short8 hfrag[4];
#pragma unroll
        for (int ks = 0; ks < 4; ++ks) {
            const float* p = h + (size_t)(n0 + c) * HID + ks * 32 + q * 8;
            hfrag[ks] = cvt8(*(const float4*)p, *(const float4*)(p + 4));
        }

        f32x4 acc[4];
#pragma unroll
        for (int ot = 0; ot < 4; ++ot) acc[ot] = (f32x4){0.f, 0.f, 0.f, 0.f};

#pragma unroll
        for (int ks = 0; ks < 4; ++ks)
#pragma unroll
            for (int ot = 0; ot < 4; ++ot)
                acc[ot] = __builtin_amdgcn_mfma_f32_16x16x32_bf16(
                    vfrag[ot][ks], hfrag[ks], acc[ot], 0, 0, 0);

        const int node = n0 + c;
#pragma unroll
        for (int ot = 0; ot < 4; ++ot) {
            int o_base = wave * 64 + ot * 16 + q * 4;
            unsigned short r0 = f2bf(acc[ot][0] + bias[ot][0]);
            unsigned short r1 = f2bf(acc[ot][1] + bias[ot][1]);
            unsigned short r2 = f2bf(acc[ot][2] + bias[ot][2]);
            unsigned short r3 = f2bf(acc[ot][3] + bias[ot][3]);
            uint2 st;
            st.x = (uint32)r0 | ((uint32)r1 << 16);
            st.y = (uint32)r2 | ((uint32)r3 << 16);
            *(uint2*)(AB + (size_t)node * 256 + o_base) = st;
        }
    }
}

// ---------------------------------------------------------------------------
// Stage 2: one wave per edge; lane i handles channels 2i,2i+1 (packed bf16 AB).
// ---------------------------------------------------------------------------
__global__ __launch_bounds__(256) void edge_stage_kernel(
    const unsigned short* __restrict__ AB,  // [N,256] bf16 bits
    const int* __restrict__ src,
    const int* __restrict__ dst,
    const float* __restrict__ W2,   // [128]
    const float* __restrict__ b2,   // [1]
    const float* __restrict__ W3,   // [1]
    const float* __restrict__ b3,   // [1]
    float* __restrict__ out,        // [E]
    int E)
{
    const int lane = threadIdx.x & 63;
    const int e = blockIdx.x * 4 + (threadIdx.x >> 6);
    if (e >= E) return;

    const int s = src[e];
    const int d = dst[e];

    const uint32 ua = *(const uint32*)(AB + (size_t)s * 256 + 2 * lane);
    const uint32 ub = *(const uint32*)(AB + (size_t)d * 256 + 128 + 2 * lane);
    const float2 w  = *(const float2*)(W2 + 2 * lane);

    float t0 = fmaxf(bflo(ua) + bflo(ub), 0.0f);
    float t1 = fmaxf(bfhi(ua) + bfhi(ub), 0.0f);
    float p  = t0 * w.x + t1 * w.y;

#pragma unroll
    for (int m = 32; m >= 1; m >>= 1) p += __shfl_xor(p, m, 64);

    if (lane == 0) {
        float y2 = fmaxf(p + b2[0], 0.0f);
        float y3 = fmaxf(W3[0] * y2 + b3[0], 0.0f);
        out[e] = 1.0f / (1.0f + __expf(-y3));
    }
}

// ---------------------------------------------------------------------------
// Fallback (ws too small): direct per-edge MLP, fp32. Correct, slow.
// ---------------------------------------------------------------------------
__global__ __launch_bounds__(256) void edge_direct_kernel(
    const float* __restrict__ h,
    const int* __restrict__ src,
    const int* __restrict__ dst,
    const float* __restrict__ W1,
    const float* __restrict__ b1,
    const float* __restrict__ W2,
    const float* __restrict__ b2,
    const float* __restrict__ W3,
    const float* __restrict__ b3,
    float* __restrict__ out,
    int E)
{
    __shared__ float x[256];
    __shared__ float red[4];
    const int e = blockIdx.x;
    if (e >= E) return;
    const int t = threadIdx.x;
    const int s = src[e];
    const int d = dst[e];

    if (t < 128) x[t] = h[(size_t)s * HID + t];
    else         x[t] = h[(size_t)d * HID + (t - 128)];
    __syncthreads();

    float contrib = 0.0f;
    if (t < 128) {
        float acc = b1[t];
        const float* wr = W1 + t * 256;
        for (int k = 0; k < 256; ++k) acc = fmaf(wr[k], x[k], acc);
        contrib = fmaxf(acc, 0.0f) * W2[t];
    }
#pragma unroll
    for (int m = 32; m >= 1; m >>= 1) contrib += __shfl_xor(contrib, m, 64);
    if ((t & 63) == 0) red[t >> 6] = contrib;
    __syncthreads();
    if (t == 0) {
        float p = red[0] + red[1] + red[2] + red[3];
        float y2 = fmaxf(p + b2[0], 0.0f);
        float y3 = fmaxf(W3[0] * y2 + b3[0], 0.0f);
        out[e] = 1.0f / (1.0f + __expf(-y3));
    }
}

extern "C" void kernel_launch(void* const* d_in, const int* in_sizes, int n_in,
                              void* d_out, int out_size, void* d_ws, size_t ws_size,
                              hipStream_t stream) {
    const float* h   = (const float*)d_in[0];
    const int*   src = (const int*)d_in[1];
    const int*   dst = (const int*)d_in[2];
    const float* W1  = (const float*)d_in[3];
    const float* b1  = (const float*)d_in[4];
    const float* W2  = (const float*)d_in[5];
    const float* b2  = (const float*)d_in[6];
    const float* W3  = (const float*)d_in[7];
    const float* b3  = (const float*)d_in[8];
    float* out = (float*)d_out;

    const int N = in_sizes[0] / HID;   // 100000
    const int E = in_sizes[1];         // 500000

    const size_t ab_bytes = (size_t)N * 256 * sizeof(unsigned short);
    if (ab_bytes <= ws_size) {
        unsigned short* AB = (unsigned short*)d_ws;
        const int node_tiles = (N + 15) / 16;
        const int nblocks = (node_tiles + NT_PER_BLOCK - 1) / NT_PER_BLOCK;
        node_stage_kernel<<<nblocks, 256, 0, stream>>>(h, W1, b1, AB, N);
        edge_stage_kernel<<<(E + 3) / 4, 256, 0, stream>>>(AB, src, dst, W2, b2, W3, b3, out, E);
    } else {
        edge_direct_kernel<<<E, 256, 0, stream>>>(h, src, dst, W1, b1, W2, b2, W3, b3, out, E);
    }
}

// Round 3
// 165.729 us; speedup vs baseline: 1.3412x; 1.3412x over previous
//
#include <hip/hip_runtime.h>
#include <hip/hip_bf16.h>

// h:[N,128] f32, src/dst:[E] i32, W1:[128,256] f32, b1:[128] f32, W2:[1,128] f32,
// b2,W3,b3: scalars f32  -> out:[E] f32
// Factorization: W1@concat(h[s],h[d]) = W1[:,:128]@h[s] + W1[:,128:]@h[d]
// Stage 1 (per node, MFMA bf16): AB[n][0:128] = W1[:,:128]@h[n] + b1 ; AB[n][128:256] = W1[:,128:]@h[n]
//   AB stored bf16 in d_ws (51.2 MB) to halve stage-2 gather traffic.
// Stage 2 (per edge): out = sigmoid(relu(W3*relu(W2 . relu(A[s]+B[d]) + b2) + b3))

#define HID 128

using short8 = __attribute__((ext_vector_type(8))) short;  // 8 bf16 = 4 VGPRs
using f32x4  = __attribute__((ext_vector_type(4))) float;

typedef unsigned int uint32;

static __device__ __forceinline__ unsigned short f2bf(float f) {  // RNE f32->bf16
    uint32 u = __float_as_uint(f);
    u += 0x7fffu + ((u >> 16) & 1u);
    return (unsigned short)(u >> 16);
}
static __device__ __forceinline__ uint32 pk2(float a, float b) {
    return ((uint32)f2bf(a)) | (((uint32)f2bf(b)) << 16);
}
static __device__ __forceinline__ float bflo(uint32 u) { return __uint_as_float(u << 16); }
static __device__ __forceinline__ float bfhi(uint32 u) { return __uint_as_float(u & 0xffff0000u); }

// ---------------------------------------------------------------------------
// Stage 1: node GEMM via MFMA.  D[o][n] = sum_k V[o][k] * h[n][k]
//   V[o][k] = W1[o&127][(o>=128?128:0)+k],  o in [0,256), k in [0,128)
// mfma_f32_16x16x32_bf16 (m89-verified): A[m=lane&15][k=quad*8+j],
//   B[k=quad*8+j][n=lane&15], C/D col=lane&15 (node), row=quad*4+reg (output).
// h tile (16 nodes x 128ch) is staged f32->bf16 through LDS ONCE per block
// (was 4x redundant per-wave loads+cvt). LDS layout: row r, ch-block j (8ch=16B)
// stored at ch offset r*256 + ((j^r)*8): XOR swizzle -> <=2-way banks (free),
// 16B-aligned b128 reads/writes.
// ---------------------------------------------------------------------------
#define NT_PER_BLOCK 10  // 16-node tiles per block

__global__ __launch_bounds__(256) void node_stage_kernel(
    const float* __restrict__ h,     // [N,128]
    const float* __restrict__ W1,    // [128,256]
    const float* __restrict__ b1,    // [128]
    unsigned short* __restrict__ AB, // [N,256] bf16 bits out
    int N)
{
    __shared__ unsigned short hs[16 * 256];  // 8 KB, xor-swizzled 16B blocks

    const int t    = threadIdx.x;
    const int lane = t & 63;
    const int wave = t >> 6;     // 0..3 -> output group wave*64
    const int c    = lane & 15;
    const int q    = lane >> 4;

    // Loop-invariant weight A-frags (fp32 load -> bf16 frag, once per block)
    short8 vfrag[4][4];
    float  bias[4][4];
#pragma unroll
    for (int ot = 0; ot < 4; ++ot) {
#pragma unroll
        for (int ks = 0; ks < 4; ++ks) {
            int o   = wave * 64 + ot * 16 + c;
            int row = o & 127;
            int col = ((o >= 128) ? 128 : 0) + ks * 32 + q * 8;
            const float* p = W1 + row * 256 + col;
            float4 f0 = *(const float4*)p;
            float4 f1 = *(const float4*)(p + 4);
            short8 v;
            v[0] = (short)f2bf(f0.x); v[1] = (short)f2bf(f0.y);
            v[2] = (short)f2bf(f0.z); v[3] = (short)f2bf(f0.w);
            v[4] = (short)f2bf(f1.x); v[5] = (short)f2bf(f1.y);
            v[6] = (short)f2bf(f1.z); v[7] = (short)f2bf(f1.w);
            vfrag[ot][ks] = v;
        }
#pragma unroll
        for (int r = 0; r < 4; ++r) {
            int o = wave * 64 + ot * 16 + q * 4 + r;
            bias[ot][r] = (o < 128) ? b1[o] : 0.0f;
        }
    }

    const int sr = t >> 4;   // staging row 0..15
    const int sj = t & 15;   // staging ch-block 0..15

    const int nt0 = blockIdx.x * NT_PER_BLOCK;
    for (int it = 0; it < NT_PER_BLOCK; ++it) {
        int n0 = (nt0 + it) * 16;
        if (n0 + 16 > N) break;  // N=100000 is a multiple of 16

        // --- stage h tile: 256 threads x 8ch, f32 -> bf16, one pass ---
        {
            const float* p = h + (size_t)(n0 + sr) * HID + sj * 8;
            float4 f0 = *(const float4*)p;
            float4 f1 = *(const float4*)(p + 4);
            uint4 st;
            st.x = pk2(f0.x, f0.y);
            st.y = pk2(f0.z, f0.w);
            st.z = pk2(f1.x, f1.y);
            st.w = pk2(f1.z, f1.w);
            *(uint4*)(hs + sr * 256 + ((sj ^ sr) * 8)) = st;
        }
        __syncthreads();

        short8 hfrag[4];
#pragma unroll
        for (int ks = 0; ks < 4; ++ks) {
            int blk = (ks * 4 + q) ^ c;  // xor-unswizzle
            hfrag[ks] = *(const short8*)(hs + c * 256 + blk * 8);
        }

        f32x4 acc[4];
#pragma unroll
        for (int ot = 0; ot < 4; ++ot) acc[ot] = (f32x4){0.f, 0.f, 0.f, 0.f};

#pragma unroll
        for (int ks = 0; ks < 4; ++ks)
#pragma unroll
            for (int ot = 0; ot < 4; ++ot)
                acc[ot] = __builtin_amdgcn_mfma_f32_16x16x32_bf16(
                    vfrag[ot][ks], hfrag[ks], acc[ot], 0, 0, 0);

        const int node = n0 + c;
#pragma unroll
        for (int ot = 0; ot < 4; ++ot) {
            int o_base = wave * 64 + ot * 16 + q * 4;
            uint2 st;
            st.x = pk2(acc[ot][0] + bias[ot][0], acc[ot][1] + bias[ot][1]);
            st.y = pk2(acc[ot][2] + bias[ot][2], acc[ot][3] + bias[ot][3]);
            *(uint2*)(AB + (size_t)node * 256 + o_base) = st;
        }
        __syncthreads();  // protect hs before next iteration's staging
    }
}

// ---------------------------------------------------------------------------
// Stage 2: 4 edges per wave, 16 lanes per edge; lane handles 8 channels via
// one uint4 (16B) load each from A-part and B-part. Reduce = 4 xor-shuffles
// shared across the 4 edges; tail once per wave (4 active lanes, coalesced
// dword stores).
// ---------------------------------------------------------------------------
__global__ __launch_bounds__(256) void edge_stage_kernel(
    const unsigned short* __restrict__ AB,  // [N,256] bf16 bits
    const int* __restrict__ src,
    const int* __restrict__ dst,
    const float* __restrict__ W2,   // [128]
    const float* __restrict__ b2,   // [1]
    const float* __restrict__ W3,   // [1]
    const float* __restrict__ b3,   // [1]
    float* __restrict__ out,        // [E]
    int E)
{
    const int lane = threadIdx.x & 63;
    const int wave = threadIdx.x >> 6;
    const int sub  = lane & 15;     // lane within edge group
    const int eg   = lane >> 4;     // edge slot 0..3 in this wave
    const int e    = blockIdx.x * 16 + wave * 4 + eg;
    if (e >= E) return;

    const int s = src[e];
    const int d = dst[e];

    const uint4 ua = *(const uint4*)(AB + (size_t)s * 256 + sub * 8);
    const uint4 ub = *(const uint4*)(AB + (size_t)d * 256 + 128 + sub * 8);
    const float4 w0 = *(const float4*)(W2 + sub * 8);
    const float4 w1 = *(const float4*)(W2 + sub * 8 + 4);

    float p;
    {
        float t0 = fmaxf(bflo(ua.x) + bflo(ub.x), 0.0f);
        float t1 = fmaxf(bfhi(ua.x) + bfhi(ub.x), 0.0f);
        float t2 = fmaxf(bflo(ua.y) + bflo(ub.y), 0.0f);
        float t3 = fmaxf(bfhi(ua.y) + bfhi(ub.y), 0.0f);
        float t4 = fmaxf(bflo(ua.z) + bflo(ub.z), 0.0f);
        float t5 = fmaxf(bfhi(ua.z) + bfhi(ub.z), 0.0f);
        float t6 = fmaxf(bflo(ua.w) + bflo(ub.w), 0.0f);
        float t7 = fmaxf(bfhi(ua.w) + bfhi(ub.w), 0.0f);
        p  = t0 * w0.x;
        p  = fmaf(t1, w0.y, p);
        p  = fmaf(t2, w0.z, p);
        p  = fmaf(t3, w0.w, p);
        p  = fmaf(t4, w1.x, p);
        p  = fmaf(t5, w1.y, p);
        p  = fmaf(t6, w1.z, p);
        p  = fmaf(t7, w1.w, p);
    }

#pragma unroll
    for (int m = 8; m >= 1; m >>= 1) p += __shfl_xor(p, m, 64);

    if (sub == 0) {
        float y2 = fmaxf(p + b2[0], 0.0f);
        float y3 = fmaxf(W3[0] * y2 + b3[0], 0.0f);
        out[e] = 1.0f / (1.0f + __expf(-y3));
    }
}

// ---------------------------------------------------------------------------
// Fallback (ws too small): direct per-edge MLP, fp32. Correct, slow.
// ---------------------------------------------------------------------------
__global__ __launch_bounds__(256) void edge_direct_kernel(
    const float* __restrict__ h,
    const int* __restrict__ src,
    const int* __restrict__ dst,
    const float* __restrict__ W1,
    const float* __restrict__ b1,
    const float* __restrict__ W2,
    const float* __restrict__ b2,
    const float* __restrict__ W3,
    const float* __restrict__ b3,
    float* __restrict__ out,
    int E)
{
    __shared__ float x[256];
    __shared__ float red[4];
    const int e = blockIdx.x;
    if (e >= E) return;
    const int t = threadIdx.x;
    const int s = src[e];
    const int d = dst[e];

    if (t < 128) x[t] = h[(size_t)s * HID + t];
    else         x[t] = h[(size_t)d * HID + (t - 128)];
    __syncthreads();

    float contrib = 0.0f;
    if (t < 128) {
        float acc = b1[t];
        const float* wr = W1 + t * 256;
        for (int k = 0; k < 256; ++k) acc = fmaf(wr[k], x[k], acc);
        contrib = fmaxf(acc, 0.0f) * W2[t];
    }
#pragma unroll
    for (int m = 32; m >= 1; m >>= 1) contrib += __shfl_xor(contrib, m, 64);
    if ((t & 63) == 0) red[t >> 6] = contrib;
    __syncthreads();
    if (t == 0) {
        float p = red[0] + red[1] + red[2] + red[3];
        float y2 = fmaxf(p + b2[0], 0.0f);
        float y3 = fmaxf(W3[0] * y2 + b3[0], 0.0f);
        out[e] = 1.0f / (1.0f + __expf(-y3));
    }
}

extern "C" void kernel_launch(void* const* d_in, const int* in_sizes, int n_in,
                              void* d_out, int out_size, void* d_ws, size_t ws_size,
                              hipStream_t stream) {
    const float* h   = (const float*)d_in[0];
    const int*   src = (const int*)d_in[1];
    const int*   dst = (const int*)d_in[2];
    const float* W1  = (const float*)d_in[3];
    const float* b1  = (const float*)d_in[4];
    const float* W2  = (const float*)d_in[5];
    const float* b2  = (const float*)d_in[6];
    const float* W3  = (const float*)d_in[7];
    const float* b3  = (const float*)d_in[8];
    float* out = (float*)d_out;

    const int N = in_sizes[0] / HID;   // 100000
    const int E = in_sizes[1];         // 500000

    const size_t ab_bytes = (size_t)N * 256 * sizeof(unsigned short);
    if (ab_bytes <= ws_size) {
        unsigned short* AB = (unsigned short*)d_ws;
        const int node_tiles = (N + 15) / 16;
        const int nblocks = (node_tiles + NT_PER_BLOCK - 1) / NT_PER_BLOCK;
        node_stage_kernel<<<nblocks, 256, 0, stream>>>(h, W1, b1, AB, N);
        edge_stage_kernel<<<(E + 15) / 16, 256, 0, stream>>>(AB, src, dst, W2, b2, W3, b3, out, E);
    } else {
        edge_direct_kernel<<<E, 256, 0, stream>>>(h, src, dst, W1, b1, W2, b2, W3, b3, out, E);
    }
}